// Round 8
// baseline (243.031 us; speedup 1.0000x reference)
//
#include <hip/hip_runtime.h>
#include <math.h>

#define N_NODES 50000
#define N_FEAT  128
#define N_EDGES 600000
#define N_POWERS 3

#define NJB 8
#define NIB 8
#define NB64 64
#define CAP64 10240                  // per (j,i)-bucket capacity: mean 9375 + 9 sigma
#define CHUNK 2048
#define NCHUNK 293                   // ceil(600000 / 2048)

#define TILES 5                      // 16-edge MFMA tiles per wave
#define EDGES_PER_BLK (4 * TILES * 16)   // 320; blocks per sub-bucket = CAP64/320 = 32

typedef _Float16 half2v __attribute__((ext_vector_type(2)));
typedef _Float16 half8  __attribute__((ext_vector_type(8)));
typedef float    f32x4  __attribute__((ext_vector_type(4)));
union HU { unsigned u; half2v h; };
union BU { unsigned u[4]; half8 h; };

__device__ __forceinline__ int slice_of(int v) { return (int)(((unsigned)v * 41u) >> 18); } // 0..7

// ---- conversion: x fp32 -> packed f16 rows; block 0 packs Wa (two layouts) ----
__global__ __launch_bounds__(256) void conv_x_plain(const float* __restrict__ x,
                                                    unsigned* __restrict__ xh,
                                                    const float* __restrict__ Wa,
                                                    unsigned* __restrict__ wah,
                                                    unsigned* __restrict__ waf) {
    const int t = blockIdx.x * 256 + threadIdx.x;   // 800000 threads exactly
    const float4* x4 = (const float4*)x;
    float4 a = x4[(size_t)t * 2];
    float4 b = x4[(size_t)t * 2 + 1];
    HU p0, p1, p2, p3;
    p0.h = half2v{(_Float16)a.x, (_Float16)a.y};
    p1.h = half2v{(_Float16)a.z, (_Float16)a.w};
    p2.h = half2v{(_Float16)b.x, (_Float16)b.y};
    p3.h = half2v{(_Float16)b.z, (_Float16)b.w};
    ((uint4*)xh)[t] = uint4{p0.u, p1.u, p2.u, p3.u};
    if (blockIdx.x == 0) {
        if (threadIdx.x < 192) {
            const int tt = threadIdx.x;
            #pragma unroll
            for (int q = 0; q < 3; ++q) {
                int idx = tt + q * 192;
                int c  = idx % 3;
                int pk = idx / 3;
                int k  = pk % 64;
                int p  = pk / 64;
                float w0 = Wa[p * 384 + (2 * k) * 3 + c];
                float w1 = Wa[p * 384 + (2 * k + 1) * 3 + c];
                HU u; u.h = half2v{(_Float16)w0, (_Float16)w1};
                wah[idx] = u.u;
            }
        }
        // waf[(p*16+n)*64 + kk] = f16pair(Wa[p][2kk][n], Wa[p][2kk+1][n]); n>=3 -> 0
        for (int w = threadIdx.x; w < 3072; w += 256) {
            int kk = w & 63;
            int pn = w >> 6;
            int n  = pn & 15;
            int p  = pn >> 4;
            float w0 = 0.f, w1 = 0.f;
            if (n < 3) {
                w0 = Wa[p * 384 + (2 * kk) * 3 + n];
                w1 = Wa[p * 384 + (2 * kk + 1) * 3 + n];
            }
            HU u; u.h = half2v{(_Float16)w0, (_Float16)w1};
            waf[w] = u.u;
        }
    }
}

// ---- pass 1: per-chunk 64-bucket histogram (LDS atomics only) ----
__global__ __launch_bounds__(256) void hist_kernel(const int* __restrict__ edge_index,
                                                   int* __restrict__ hist) {
    __shared__ int lh[NB64];
    const int p = blockIdx.y, chunk = blockIdx.x;
    if (threadIdx.x < NB64) lh[threadIdx.x] = 0;
    __syncthreads();
    const int* ej = edge_index + (size_t)p * 2 * N_EDGES;
    const int* ei = ej + N_EDGES;
    const int base = chunk * CHUNK;
    #pragma unroll
    for (int k = 0; k < 8; ++k) {
        const int e = base + k * 256 + threadIdx.x;
        if (e < N_EDGES) {
            const int j = __builtin_nontemporal_load(ej + e);
            const int i = __builtin_nontemporal_load(ei + e);
            atomicAdd(&lh[slice_of(j) * NIB + slice_of(i)], 1);
        }
    }
    __syncthreads();
    if (threadIdx.x < NB64)
        hist[(p * NB64 + threadIdx.x) * NCHUNK + chunk] = lh[threadIdx.x];
}

// ---- pass 2: exclusive scan over chunks per (p,b); 192 single-wave blocks ----
__global__ __launch_bounds__(64) void scan_hist(int* __restrict__ hist,
                                                int* __restrict__ cur) {
    const int pb = blockIdx.x;
    const int lane = threadIdx.x;
    int* h = hist + pb * NCHUNK;
    int carry = 0;
    for (int t = 0; t < NCHUNK; t += 64) {
        const int c = t + lane;
        int v = (c < NCHUNK) ? h[c] : 0;
        int s = v;
        #pragma unroll
        for (int d = 1; d < 64; d <<= 1) {
            int u = __shfl_up(s, d, 64);
            if (lane >= d) s += u;
        }
        if (c < NCHUNK) h[c] = carry + (s - v);
        carry += __shfl(s, 63, 64);
    }
    if (lane == 0) cur[pb] = carry;
}

// ---- pass 3: deterministic scatter, packed u64 payload ----
__global__ __launch_bounds__(256) void scatter_pass(const int* __restrict__ edge_index,
                                                    const int* __restrict__ hist,
                                                    unsigned long long* __restrict__ su) {
    __shared__ int lc[NB64];
    const int p = blockIdx.y, chunk = blockIdx.x;
    if (threadIdx.x < NB64) lc[threadIdx.x] = 0;
    __syncthreads();
    const int* ej = edge_index + (size_t)p * 2 * N_EDGES;
    const int* ei = ej + N_EDGES;
    const int base = chunk * CHUNK;
    #pragma unroll
    for (int k = 0; k < 8; ++k) {
        const int e = base + k * 256 + threadIdx.x;
        if (e < N_EDGES) {
            const int j = __builtin_nontemporal_load(ej + e);
            const int i = __builtin_nontemporal_load(ei + e);
            const int b = slice_of(j) * NIB + slice_of(i);
            const int pos = atomicAdd(&lc[b], 1);   // LDS atomic: rank within chunk
            const int off = hist[(p * NB64 + b) * NCHUNK + chunk];
            const size_t slot = (size_t)(p * NB64 + b) * CAP64 + off + pos;
            su[slot] = (unsigned long long)(((unsigned)i << 16) | (unsigned)j)
                     | ((unsigned long long)(unsigned)e << 32);
        }
    }
}

template<int PAT>
__device__ __forceinline__ float swz(float v) {
    return __int_as_float(__builtin_amdgcn_ds_swizzle(__float_as_int(v), PAT));
}

// packed abs-diff of 8 f16
__device__ __forceinline__ half8 mk_d(uint4 qa, uint4 qb) {
    BU d;
    {
        HU a, b, r;
        a.u = qa.x; b.u = qb.x; r.h = a.h - b.h; d.u[0] = r.u & 0x7fff7fffu;
        a.u = qa.y; b.u = qb.y; r.h = a.h - b.h; d.u[1] = r.u & 0x7fff7fffu;
        a.u = qa.z; b.u = qb.z; r.h = a.h - b.h; d.u[2] = r.u & 0x7fff7fffu;
        a.u = qa.w; b.u = qb.w; r.h = a.h - b.h; d.u[3] = r.u & 0x7fff7fffu;
    }
    return d.h;
}

// MFMA main kernel, software-pipelined. blockIdx.x&7 = j-slice (XCD affinity);
// blocks within a j-slice walk i-slices in order (L2 i-phase locality).
__global__ __launch_bounds__(256) void adj_kernel_mfma(
    const unsigned* __restrict__ xh,        // (50000, 64) packed f16
    const unsigned long long* __restrict__ su,
    const int* __restrict__ cur,
    const unsigned* __restrict__ waf,       // B-operand layout
    const float* __restrict__ ba,
    const float* __restrict__ Wb,
    const float* __restrict__ bb,
    float* __restrict__ out)
{
    __shared__ float lw[64];

    const int p      = blockIdx.y;
    const int jb     = blockIdx.x & 7;
    const int within = blockIdx.x >> 3;     // 0..255
    const int ib     = within >> 5;         // i-slice phase 0..7
    const int kblk   = within & 31;
    const int tid  = threadIdx.x;
    const int lane = tid & 63;
    const int wave = tid >> 6;
    const int c    = lane & 15;   // MFMA n-index / edge-in-tile
    const int quad = lane >> 4;   // MFMA k-slice index

    const int bidx  = (p * NJB + jb) * NIB + ib;
    const int count = cur[bidx];
    const int base  = kblk * EDGES_PER_BLK;
    if (base >= count) return;

    // B fragments: Wa^T padded, pinned in VGPRs.
    BU bf[4];
    {
        const unsigned* wp = waf + (size_t)(p * 16 + c) * 64 + quad * 4;
        #pragma unroll
        for (int ks = 0; ks < 4; ++ks) {
            bf[ks].u[0] = wp[ks * 16 + 0];
            bf[ks].u[1] = wp[ks * 16 + 1];
            bf[ks].u[2] = wp[ks * 16 + 2];
            bf[ks].u[3] = wp[ks * 16 + 3];
        }
        #pragma unroll
        for (int ks = 0; ks < 4; ++ks)
            asm volatile("" : "+v"(bf[ks].u[0]), "+v"(bf[ks].u[1]),
                              "+v"(bf[ks].u[2]), "+v"(bf[ks].u[3]));
    }

    const float ba0 = ba[p * 3 + 0], ba1 = ba[p * 3 + 1], ba2 = ba[p * 3 + 2];
    const float wb0 = Wb[p * 3 + 0], wb1 = Wb[p * 3 + 1], wb2 = Wb[p * 3 + 2];
    const float bbp = bb[p];
    const float ba_v = (c == 0) ? ba0 : ((c == 1) ? ba1 : ((c == 2) ? ba2 : 0.f));
    const float wb_v = (c == 0) ? wb0 : ((c == 1) ? wb1 : ((c == 2) ? wb2 : 0.f));

    const unsigned long long* sup = su + (size_t)bidx * CAP64;
    float* outp = out + (size_t)p * N_EDGES;
    const int cm1 = count - 1;
    const int tb  = base + wave * 16;

    // ---- pipeline prologue: payload + rows for tile 0, payload for tile 1 ----
    unsigned long long q_cur = sup[min(tb + c, cm1)];
    uint4 A[4], B[4];
    {
        const int jc = (int)(q_cur & 0xFFFFu);
        const int ic = (int)((q_cur >> 16) & 0xFFFFu);
        const uint4* rj = (const uint4*)(xh + ((size_t)jc << 6)) + quad;
        const uint4* ri = (const uint4*)(xh + ((size_t)ic << 6)) + quad;
        #pragma unroll
        for (int ks = 0; ks < 4; ++ks) { A[ks] = rj[ks * 4]; B[ks] = ri[ks * 4]; }
    }
    unsigned long long q_nxt = sup[min(tb + 64 + c, cm1)];

    #pragma unroll
    for (int t = 0; t < TILES; ++t) {
        // issue next tile's row loads before touching this tile's data
        uint4 A1[4], B1[4];
        if (t + 1 < TILES) {
            const int jn = (int)(q_nxt & 0xFFFFu);
            const int in_ = (int)((q_nxt >> 16) & 0xFFFFu);
            const uint4* rj = (const uint4*)(xh + ((size_t)jn << 6)) + quad;
            const uint4* ri = (const uint4*)(xh + ((size_t)in_ << 6)) + quad;
            #pragma unroll
            for (int ks = 0; ks < 4; ++ks) { A1[ks] = rj[ks * 4]; B1[ks] = ri[ks * 4]; }
        }
        unsigned long long q_nn = (t + 2 < TILES) ? sup[min(tb + (t + 2) * 64 + c, cm1)] : q_nxt;

        const int e_cur = (int)(q_cur >> 32);

        f32x4 C = {0.f, 0.f, 0.f, 0.f};
        #pragma unroll
        for (int ks = 0; ks < 4; ++ks)
            C = __builtin_amdgcn_mfma_f32_16x16x32_f16(mk_d(A[ks], B[ks]), bf[ks].h, C, 0, 0, 0);

        // epilogue: relu + Wb-weighted col sum (butterfly xor1,xor2 over 4-col groups)
        float val[4];
        #pragma unroll
        for (int r = 0; r < 4; ++r) {
            val[r] = fmaxf(C[r] + ba_v, 0.f) * wb_v;
            val[r] += swz<0x041F>(val[r]);   // xor 1
            val[r] += swz<0x081F>(val[r]);   // xor 2
        }
        if (c == 0) {
            #pragma unroll
            for (int r = 0; r < 4; ++r) {
                float s = val[r] + bbp;
                lw[wave * 16 + quad * 4 + r] = 1.f / (1.f + __expf(-s));
            }
        }
        float wv = lw[wave * 16 + c];
        if (quad == 0 && (tb + t * 64 + c) < count)
            __builtin_nontemporal_store(wv, outp + e_cur);

        q_cur = q_nxt; q_nxt = q_nn;
        #pragma unroll
        for (int ks = 0; ks < 4; ++ks) { A[ks] = A1[ks]; B[ks] = B1[ks]; }
    }
}

// ---- round-4 path (no sorting) for mid-size ws ----
__device__ __forceinline__ void dot3_8(const uint4& qa0, const uint4& qa1,
                                       const uint4& qb0, const uint4& qb1,
                                       const HU wa[8][3],
                                       float& h0, float& h1, float& h2) {
    unsigned ua[8] = {qa0.x, qa0.y, qa0.z, qa0.w, qa1.x, qa1.y, qa1.z, qa1.w};
    unsigned ub[8] = {qb0.x, qb0.y, qb0.z, qb0.w, qb1.x, qb1.y, qb1.z, qb1.w};
    h0 = 0.f; h1 = 0.f; h2 = 0.f;
    #pragma unroll
    for (int k = 0; k < 8; ++k) {
        HU a, b, d;
        a.u = ua[k]; b.u = ub[k];
        d.h = a.h - b.h;
        d.u &= 0x7fff7fffu;
        h0 = __builtin_amdgcn_fdot2(d.h, wa[k][0].h, h0, false);
        h1 = __builtin_amdgcn_fdot2(d.h, wa[k][1].h, h1, false);
        h2 = __builtin_amdgcn_fdot2(d.h, wa[k][2].h, h2, false);
    }
}

__global__ __launch_bounds__(256) void adj_kernel_f16(
    const unsigned* __restrict__ xh,
    const unsigned* __restrict__ wah,
    const int*   __restrict__ edge_index,
    const float* __restrict__ ba,
    const float* __restrict__ Wb,
    const float* __restrict__ bb,
    float* __restrict__ out)
{
    const int p    = blockIdx.y;
    const int tid  = threadIdx.x;
    const int lane = tid & 63;
    const int wave = tid >> 6;
    const int sub  = lane & 7;
    const int grp  = lane >> 3;

    HU wa[8][3];
    {
        const unsigned* wp = wah + ((size_t)p * 64 + sub * 8) * 3;
        #pragma unroll
        for (int k = 0; k < 8; ++k) {
            wa[k][0].u = wp[k * 3 + 0];
            wa[k][1].u = wp[k * 3 + 1];
            wa[k][2].u = wp[k * 3 + 2];
        }
        #pragma unroll
        for (int k = 0; k < 8; ++k)
            asm volatile("" : "+v"(wa[k][0].u), "+v"(wa[k][1].u), "+v"(wa[k][2].u));
    }

    const float ba0 = ba[p * 3 + 0], ba1 = ba[p * 3 + 1], ba2 = ba[p * 3 + 2];
    const float wb0 = Wb[p * 3 + 0], wb1 = Wb[p * 3 + 1], wb2 = Wb[p * 3 + 2];
    const float bbp = bb[p];

    const int* ej = edge_index + (size_t)p * 2 * N_EDGES;
    const int* ei = ej + N_EDGES;
    float* outp = out + (size_t)p * N_EDGES;

    const int e_blk = blockIdx.x * 320;
    const int eoff  = wave * 8 + grp;
    const int roff  = sub * 8;

    #pragma unroll
    for (int it = 0; it < 5; ++it) {
        const int e1 = e_blk + it * 64 + eoff;
        const int e2 = e1 + 32;
        const int j1 = __builtin_nontemporal_load(ej + e1);
        const int i1 = __builtin_nontemporal_load(ei + e1);
        const int j2 = __builtin_nontemporal_load(ej + e2);
        const int i2 = __builtin_nontemporal_load(ei + e2);

        const uint4* rj1 = (const uint4*)(xh + ((size_t)j1 << 6) + roff);
        const uint4* ri1 = (const uint4*)(xh + ((size_t)i1 << 6) + roff);
        const uint4* rj2 = (const uint4*)(xh + ((size_t)j2 << 6) + roff);
        const uint4* ri2 = (const uint4*)(xh + ((size_t)i2 << 6) + roff);
        uint4 a0 = rj1[0], a1 = rj1[1];
        uint4 b0 = ri1[0], b1 = ri1[1];
        uint4 c0 = rj2[0], c1 = rj2[1];
        uint4 d0 = ri2[0], d1 = ri2[1];

        float h0a, h1a, h2a, h0b, h1b, h2b;
        dot3_8(a0, a1, b0, b1, wa, h0a, h1a, h2a);
        dot3_8(c0, c1, d0, d1, wa, h0b, h1b, h2b);

        h0a += swz<0x041F>(h0a); h1a += swz<0x041F>(h1a); h2a += swz<0x041F>(h2a);
        h0b += swz<0x041F>(h0b); h1b += swz<0x041F>(h1b); h2b += swz<0x041F>(h2b);
        h0a += swz<0x081F>(h0a); h1a += swz<0x081F>(h1a); h2a += swz<0x081F>(h2a);
        h0b += swz<0x081F>(h0b); h1b += swz<0x081F>(h1b); h2b += swz<0x081F>(h2b);
        h0a += swz<0x101F>(h0a); h1a += swz<0x101F>(h1a); h2a += swz<0x101F>(h2a);
        h0b += swz<0x101F>(h0b); h1b += swz<0x101F>(h1b); h2b += swz<0x101F>(h2b);

        if (sub == 0) {
            float r0 = fmaxf(h0a + ba0, 0.f);
            float r1 = fmaxf(h1a + ba1, 0.f);
            float r2 = fmaxf(h2a + ba2, 0.f);
            float s  = fmaf(r0, wb0, fmaf(r1, wb1, fmaf(r2, wb2, bbp)));
            __builtin_nontemporal_store(1.f / (1.f + __expf(-s)), outp + e1);
            r0 = fmaxf(h0b + ba0, 0.f);
            r1 = fmaxf(h1b + ba1, 0.f);
            r2 = fmaxf(h2b + ba2, 0.f);
            s  = fmaf(r0, wb0, fmaf(r1, wb1, fmaf(r2, wb2, bbp)));
            __builtin_nontemporal_store(1.f / (1.f + __expf(-s)), outp + e2);
        }
    }
}

// ---- fp32 fallback (no workspace) ----
__global__ __launch_bounds__(256) void adj_kernel_f32(
    const float* __restrict__ x,
    const int*   __restrict__ edge_index,
    const float* __restrict__ Wa,
    const float* __restrict__ ba,
    const float* __restrict__ Wb,
    const float* __restrict__ bb,
    float* __restrict__ out)
{
    const int p    = blockIdx.y;
    const int tid  = threadIdx.x;
    const int lane = tid & 63;
    const int wave = tid >> 6;
    const int sub  = lane & 15;
    const int grp  = lane >> 4;
    const int f0 = sub * 8;

    const float* Wap = Wa + (size_t)p * N_FEAT * 3;
    float wa0[8], wa1[8], wa2[8];
    #pragma unroll
    for (int k = 0; k < 8; ++k) {
        wa0[k] = Wap[(f0 + k) * 3 + 0];
        wa1[k] = Wap[(f0 + k) * 3 + 1];
        wa2[k] = Wap[(f0 + k) * 3 + 2];
    }
    const float ba0 = ba[p * 3 + 0], ba1 = ba[p * 3 + 1], ba2 = ba[p * 3 + 2];
    const float wb0 = Wb[p * 3 + 0], wb1 = Wb[p * 3 + 1], wb2 = Wb[p * 3 + 2];
    const float bbp = bb[p];

    const int e = blockIdx.x * 16 + wave * 4 + grp;
    const int* ej = edge_index + (size_t)p * 2 * N_EDGES;
    const int* ei = ej + N_EDGES;
    const int j = ej[e];
    const int i = ei[e];

    const float4* xj = (const float4*)(x + (size_t)j * N_FEAT + f0);
    const float4* xi = (const float4*)(x + (size_t)i * N_FEAT + f0);
    float4 a0 = xj[0], a1 = xj[1];
    float4 b0 = xi[0], b1 = xi[1];

    float d[8];
    d[0] = fabsf(a0.x - b0.x); d[1] = fabsf(a0.y - b0.y);
    d[2] = fabsf(a0.z - b0.z); d[3] = fabsf(a0.w - b0.w);
    d[4] = fabsf(a1.x - b1.x); d[5] = fabsf(a1.y - b1.y);
    d[6] = fabsf(a1.z - b1.z); d[7] = fabsf(a1.w - b1.w);

    float h0 = 0.f, h1 = 0.f, h2 = 0.f;
    #pragma unroll
    for (int k = 0; k < 8; ++k) {
        h0 = fmaf(d[k], wa0[k], h0);
        h1 = fmaf(d[k], wa1[k], h1);
        h2 = fmaf(d[k], wa2[k], h2);
    }
    #pragma unroll
    for (int m = 1; m < 16; m <<= 1) {
        h0 += __shfl_xor(h0, m, 64);
        h1 += __shfl_xor(h1, m, 64);
        h2 += __shfl_xor(h2, m, 64);
    }
    if (sub == 0) {
        float r0 = fmaxf(h0 + ba0, 0.f);
        float r1 = fmaxf(h1 + ba1, 0.f);
        float r2 = fmaxf(h2 + ba2, 0.f);
        float s  = fmaf(r0, wb0, fmaf(r1, wb1, fmaf(r2, wb2, bbp)));
        float w  = 1.f / (1.f + expf(-s));
        out[(size_t)p * N_EDGES + e] = w;
    }
}

extern "C" void kernel_launch(void* const* d_in, const int* in_sizes, int n_in,
                              void* d_out, int out_size, void* d_ws, size_t ws_size,
                              hipStream_t stream) {
    const float* x          = (const float*)d_in[0];
    const int*   edge_index = (const int*)d_in[1];
    const float* Wa         = (const float*)d_in[2];
    const float* ba         = (const float*)d_in[3];
    const float* Wb         = (const float*)d_in[4];
    const float* bb         = (const float*)d_in[5];
    float* out = (float*)d_out;

    const size_t x_bytes    = (size_t)N_NODES * N_FEAT * 2;                 // 12,800,000
    const size_t su_bytes   = (size_t)N_POWERS * NB64 * CAP64 * 8;          // 15,728,640
    const size_t wah_bytes  = 2304;
    const size_t waf_bytes  = 12288;
    const size_t hist_bytes = (size_t)N_POWERS * NB64 * NCHUNK * 4;         // 225,024
    const size_t cur_bytes  = NB64 * N_POWERS * 4;
    const size_t need_full  = x_bytes + su_bytes + wah_bytes + waf_bytes + hist_bytes + cur_bytes;

    if (ws_size >= need_full) {
        char* w = (char*)d_ws;
        unsigned* xh = (unsigned*)w;
        unsigned long long* su = (unsigned long long*)(w + x_bytes);
        unsigned* wah = (unsigned*)(w + x_bytes + su_bytes);
        unsigned* waf = (unsigned*)(w + x_bytes + su_bytes + wah_bytes);
        int* hist = (int*)(w + x_bytes + su_bytes + wah_bytes + waf_bytes);
        int* cur  = (int*)(w + x_bytes + su_bytes + wah_bytes + waf_bytes + hist_bytes);

        conv_x_plain<<<N_NODES * N_FEAT / 2048, 256, 0, stream>>>(x, xh, Wa, wah, waf);
        hist_kernel<<<dim3(NCHUNK, N_POWERS), 256, 0, stream>>>(edge_index, hist);
        scan_hist<<<NB64 * N_POWERS, 64, 0, stream>>>(hist, cur);
        scatter_pass<<<dim3(NCHUNK, N_POWERS), 256, 0, stream>>>(edge_index, hist, su);
        dim3 grid(NJB * NIB * (CAP64 / EDGES_PER_BLK), N_POWERS);   // (2048, 3)
        adj_kernel_mfma<<<grid, 256, 0, stream>>>(xh, su, cur, waf, ba, Wb, bb, out);
    } else if (ws_size >= x_bytes + wah_bytes + waf_bytes) {
        unsigned* xh  = (unsigned*)d_ws;
        unsigned* wah = (unsigned*)((char*)d_ws + x_bytes);
        unsigned* waf = (unsigned*)((char*)d_ws + x_bytes + wah_bytes);
        conv_x_plain<<<N_NODES * N_FEAT / 2048, 256, 0, stream>>>(x, xh, Wa, wah, waf);
        dim3 grid(N_EDGES / 320, N_POWERS);
        adj_kernel_f16<<<grid, 256, 0, stream>>>(xh, wah, edge_index, ba, Wb, bb, out);
    } else {
        dim3 grid((N_EDGES + 15) / 16, N_POWERS);
        adj_kernel_f32<<<grid, 256, 0, stream>>>(x, edge_index, Wa, ba, Wb, bb, out);
    }
}

// Round 10
// 197.983 us; speedup vs baseline: 1.2275x; 1.2275x over previous
//
#include <hip/hip_runtime.h>
#include <math.h>

#define N_NODES 50000
#define N_FEAT  128
#define N_EDGES 600000
#define N_POWERS 3

#define NJB 8
#define NIB 8
#define NB64 64
#define CAP64 10240                  // per (j,i)-bucket capacity (round-8 run proves counts fit)
#define CHUNK 2048
#define NCHUNK 293                   // ceil(600000 / 2048)

#define EDGES_PER_BLK 320            // blocks per sub-bucket = CAP64/320 = 32

typedef _Float16 half2v __attribute__((ext_vector_type(2)));
union HU { unsigned u; half2v h; };

__device__ __forceinline__ int slice_of(int v) { return (int)(((unsigned)v * 41u) >> 18); } // 0..7

// ---- conversion: x fp32 -> packed f16 rows; block 0 packs Wa ----
__global__ __launch_bounds__(256) void conv_x_plain(const float* __restrict__ x,
                                                    unsigned* __restrict__ xh,
                                                    const float* __restrict__ Wa,
                                                    unsigned* __restrict__ wah) {
    const int t = blockIdx.x * 256 + threadIdx.x;   // 800000 threads exactly
    const float4* x4 = (const float4*)x;
    float4 a = x4[(size_t)t * 2];
    float4 b = x4[(size_t)t * 2 + 1];
    HU p0, p1, p2, p3;
    p0.h = half2v{(_Float16)a.x, (_Float16)a.y};
    p1.h = half2v{(_Float16)a.z, (_Float16)a.w};
    p2.h = half2v{(_Float16)b.x, (_Float16)b.y};
    p3.h = half2v{(_Float16)b.z, (_Float16)b.w};
    ((uint4*)xh)[t] = uint4{p0.u, p1.u, p2.u, p3.u};
    if (blockIdx.x == 0 && threadIdx.x < 192) {
        const int tt = threadIdx.x;
        #pragma unroll
        for (int q = 0; q < 3; ++q) {
            int idx = tt + q * 192;            // 576 entries: (p,k,c)
            int c  = idx % 3;
            int pk = idx / 3;
            int k  = pk % 64;
            int p  = pk / 64;
            float w0 = Wa[p * 384 + (2 * k) * 3 + c];
            float w1 = Wa[p * 384 + (2 * k + 1) * 3 + c];
            HU u; u.h = half2v{(_Float16)w0, (_Float16)w1};
            wah[idx] = u.u;
        }
    }
}

// ---- pass 1: per-chunk 64-bucket histogram (LDS atomics only) ----
__global__ __launch_bounds__(256) void hist_kernel(const int* __restrict__ edge_index,
                                                   int* __restrict__ hist) {
    __shared__ int lh[NB64];
    const int p = blockIdx.y, chunk = blockIdx.x;
    if (threadIdx.x < NB64) lh[threadIdx.x] = 0;
    __syncthreads();
    const int* ej = edge_index + (size_t)p * 2 * N_EDGES;
    const int* ei = ej + N_EDGES;
    const int base = chunk * CHUNK;
    #pragma unroll
    for (int k = 0; k < 8; ++k) {
        const int e = base + k * 256 + threadIdx.x;
        if (e < N_EDGES) {
            const int j = __builtin_nontemporal_load(ej + e);
            const int i = __builtin_nontemporal_load(ei + e);
            atomicAdd(&lh[slice_of(j) * NIB + slice_of(i)], 1);
        }
    }
    __syncthreads();
    if (threadIdx.x < NB64)
        hist[(p * NB64 + threadIdx.x) * NCHUNK + chunk] = lh[threadIdx.x];
}

// ---- pass 2: exclusive scan over chunks per (p,b); 192 single-wave blocks ----
__global__ __launch_bounds__(64) void scan_hist(int* __restrict__ hist,
                                                int* __restrict__ cur) {
    const int pb = blockIdx.x;
    const int lane = threadIdx.x;
    int* h = hist + pb * NCHUNK;
    int carry = 0;
    for (int t = 0; t < NCHUNK; t += 64) {
        const int c = t + lane;
        int v = (c < NCHUNK) ? h[c] : 0;
        int s = v;
        #pragma unroll
        for (int d = 1; d < 64; d <<= 1) {
            int u = __shfl_up(s, d, 64);
            if (lane >= d) s += u;
        }
        if (c < NCHUNK) h[c] = carry + (s - v);
        carry += __shfl(s, 63, 64);
    }
    if (lane == 0) cur[pb] = carry;
}

// ---- pass 3: deterministic scatter, packed u64 payload; capacity-guarded ----
__global__ __launch_bounds__(256) void scatter_pass(const int* __restrict__ edge_index,
                                                    const int* __restrict__ hist,
                                                    unsigned long long* __restrict__ su) {
    __shared__ int lc[NB64];
    const int p = blockIdx.y, chunk = blockIdx.x;
    if (threadIdx.x < NB64) lc[threadIdx.x] = 0;
    __syncthreads();
    const int* ej = edge_index + (size_t)p * 2 * N_EDGES;
    const int* ei = ej + N_EDGES;
    const int base = chunk * CHUNK;
    #pragma unroll
    for (int k = 0; k < 8; ++k) {
        const int e = base + k * 256 + threadIdx.x;
        if (e < N_EDGES) {
            const int j = __builtin_nontemporal_load(ej + e);
            const int i = __builtin_nontemporal_load(ei + e);
            const int b = slice_of(j) * NIB + slice_of(i);
            const int pos = atomicAdd(&lc[b], 1);   // LDS atomic: rank within chunk
            const int off = hist[(p * NB64 + b) * NCHUNK + chunk] + pos;
            if (off < CAP64) {                      // inert guard (counts fit per round-8 run)
                const size_t slot = (size_t)(p * NB64 + b) * CAP64 + off;
                su[slot] = (unsigned long long)(((unsigned)i << 16) | (unsigned)j)
                         | ((unsigned long long)(unsigned)e << 32);
            }
        }
    }
}

template<int PAT>
__device__ __forceinline__ float swz(float v) {
    return __int_as_float(__builtin_amdgcn_ds_swizzle(__float_as_int(v), PAT));
}

__device__ __forceinline__ void dot3_8(const uint4& qa0, const uint4& qa1,
                                       const uint4& qb0, const uint4& qb1,
                                       const HU wa[8][3],
                                       float& h0, float& h1, float& h2) {
    unsigned ua[8] = {qa0.x, qa0.y, qa0.z, qa0.w, qa1.x, qa1.y, qa1.z, qa1.w};
    unsigned ub[8] = {qb0.x, qb0.y, qb0.z, qb0.w, qb1.x, qb1.y, qb1.z, qb1.w};
    h0 = 0.f; h1 = 0.f; h2 = 0.f;
    #pragma unroll
    for (int k = 0; k < 8; ++k) {
        HU a, b, d;
        a.u = ua[k]; b.u = ub[k];
        d.h = a.h - b.h;
        d.u &= 0x7fff7fffu;               // packed abs
        h0 = __builtin_amdgcn_fdot2(d.h, wa[k][0].h, h0, false);
        h1 = __builtin_amdgcn_fdot2(d.h, wa[k][1].h, h1, false);
        h2 = __builtin_amdgcn_fdot2(d.h, wa[k][2].h, h2, false);
    }
}

// Main: round-6 compute structure fed by the (j,i)-sorted stream.
// blockIdx.x&7 = j-slice (XCD affinity); blocks within walk i-phases in order.
__global__ __launch_bounds__(256) void adj_kernel_f16s(
    const unsigned* __restrict__ xh,        // (50000, 64) packed f16
    const unsigned long long* __restrict__ su,
    const int* __restrict__ cur,
    const unsigned* __restrict__ wah,       // (P, 64, 3) packed f16 pairs
    const float* __restrict__ ba,
    const float* __restrict__ Wb,
    const float* __restrict__ bb,
    float* __restrict__ out)                // (P, E)
{
    const int p      = blockIdx.y;
    const int jb     = blockIdx.x & 7;
    const int within = blockIdx.x >> 3;     // 0..255
    const int ib     = within >> 5;         // i-slice phase 0..7
    const int kblk   = within & 31;
    const int tid  = threadIdx.x;
    const int lane = tid & 63;
    const int wave = tid >> 6;
    const int sub  = lane & 7;     // lane within edge group (8 lanes/edge)
    const int grp  = lane >> 3;    // 8 edge groups per wave

    const int bidx  = (p * NJB + jb) * NIB + ib;
    const int count = min(cur[bidx], CAP64);   // defensive clamp
    const int base  = kblk * EDGES_PER_BLK;
    if (base >= count) return;

    HU wa[8][3];
    {
        const unsigned* wp = wah + ((size_t)p * 64 + sub * 8) * 3;
        #pragma unroll
        for (int k = 0; k < 8; ++k) {
            wa[k][0].u = wp[k * 3 + 0];
            wa[k][1].u = wp[k * 3 + 1];
            wa[k][2].u = wp[k * 3 + 2];
        }
        #pragma unroll
        for (int k = 0; k < 8; ++k)
            asm volatile("" : "+v"(wa[k][0].u), "+v"(wa[k][1].u), "+v"(wa[k][2].u));
    }

    const float ba0 = ba[p * 3 + 0], ba1 = ba[p * 3 + 1], ba2 = ba[p * 3 + 2];
    const float wb0 = Wb[p * 3 + 0], wb1 = Wb[p * 3 + 1], wb2 = Wb[p * 3 + 2];
    const float bbp = bb[p];

    const unsigned long long* sup = su + (size_t)bidx * CAP64;
    float* outp = out + (size_t)p * N_EDGES;

    const int eoff = wave * 8 + grp;
    const int roff = sub * 8;   // uint offset of this lane's 32B slice in a row
    const int cm1  = count - 1;

    #pragma unroll
    for (int it = 0; it < 5; ++it) {
        const int r1 = base + it * 64 + eoff;
        const int r2 = r1 + 32;
        const bool v1 = r1 < count;
        const bool v2 = r2 < count;

        // single u64 payload per edge (j | i<<16 | e<<32); clamp keeps loads in-bucket
        const unsigned long long q1 = __builtin_nontemporal_load(sup + min(r1, cm1));
        const unsigned long long q2 = __builtin_nontemporal_load(sup + min(r2, cm1));
        const int j1 = (int)(q1 & 0xFFFFu);
        const int i1 = (int)((q1 >> 16) & 0xFFFFu);
        const int e1 = (int)(q1 >> 32);
        const int j2 = (int)(q2 & 0xFFFFu);
        const int i2 = (int)((q2 >> 16) & 0xFFFFu);
        const int e2 = (int)(q2 >> 32);

        const uint4* rj1 = (const uint4*)(xh + ((size_t)j1 << 6) + roff);
        const uint4* ri1 = (const uint4*)(xh + ((size_t)i1 << 6) + roff);
        const uint4* rj2 = (const uint4*)(xh + ((size_t)j2 << 6) + roff);
        const uint4* ri2 = (const uint4*)(xh + ((size_t)i2 << 6) + roff);
        uint4 a0 = rj1[0], a1 = rj1[1];
        uint4 b0 = ri1[0], b1 = ri1[1];
        uint4 c0 = rj2[0], c1 = rj2[1];
        uint4 d0 = ri2[0], d1 = ri2[1];

        float h0a, h1a, h2a, h0b, h1b, h2b;
        dot3_8(a0, a1, b0, b1, wa, h0a, h1a, h2a);
        dot3_8(c0, c1, d0, d1, wa, h0b, h1b, h2b);

        // reduce across the 8-lane group (xor 1,2,4 stay in-group)
        h0a += swz<0x041F>(h0a); h1a += swz<0x041F>(h1a); h2a += swz<0x041F>(h2a);
        h0b += swz<0x041F>(h0b); h1b += swz<0x041F>(h1b); h2b += swz<0x041F>(h2b);
        h0a += swz<0x081F>(h0a); h1a += swz<0x081F>(h1a); h2a += swz<0x081F>(h2a);
        h0b += swz<0x081F>(h0b); h1b += swz<0x081F>(h1b); h2b += swz<0x081F>(h2b);
        h0a += swz<0x101F>(h0a); h1a += swz<0x101F>(h1a); h2a += swz<0x101F>(h2a);
        h0b += swz<0x101F>(h0b); h1b += swz<0x101F>(h1b); h2b += swz<0x101F>(h2b);

        if (sub == 0) {
            if (v1) {
                float r0 = fmaxf(h0a + ba0, 0.f);
                float r1f = fmaxf(h1a + ba1, 0.f);
                float r2f = fmaxf(h2a + ba2, 0.f);
                float s  = fmaf(r0, wb0, fmaf(r1f, wb1, fmaf(r2f, wb2, bbp)));
                __builtin_nontemporal_store(1.f / (1.f + __expf(-s)), outp + e1);
            }
            if (v2) {
                float r0 = fmaxf(h0b + ba0, 0.f);
                float r1f = fmaxf(h1b + ba1, 0.f);
                float r2f = fmaxf(h2b + ba2, 0.f);
                float s  = fmaf(r0, wb0, fmaf(r1f, wb1, fmaf(r2f, wb2, bbp)));
                __builtin_nontemporal_store(1.f / (1.f + __expf(-s)), outp + e2);
            }
        }
    }
}

// ---- round-4 path (no sorting) for mid-size ws ----
__global__ __launch_bounds__(256) void adj_kernel_f16(
    const unsigned* __restrict__ xh,
    const unsigned* __restrict__ wah,
    const int*   __restrict__ edge_index,
    const float* __restrict__ ba,
    const float* __restrict__ Wb,
    const float* __restrict__ bb,
    float* __restrict__ out)
{
    const int p    = blockIdx.y;
    const int tid  = threadIdx.x;
    const int lane = tid & 63;
    const int wave = tid >> 6;
    const int sub  = lane & 7;
    const int grp  = lane >> 3;

    HU wa[8][3];
    {
        const unsigned* wp = wah + ((size_t)p * 64 + sub * 8) * 3;
        #pragma unroll
        for (int k = 0; k < 8; ++k) {
            wa[k][0].u = wp[k * 3 + 0];
            wa[k][1].u = wp[k * 3 + 1];
            wa[k][2].u = wp[k * 3 + 2];
        }
        #pragma unroll
        for (int k = 0; k < 8; ++k)
            asm volatile("" : "+v"(wa[k][0].u), "+v"(wa[k][1].u), "+v"(wa[k][2].u));
    }

    const float ba0 = ba[p * 3 + 0], ba1 = ba[p * 3 + 1], ba2 = ba[p * 3 + 2];
    const float wb0 = Wb[p * 3 + 0], wb1 = Wb[p * 3 + 1], wb2 = Wb[p * 3 + 2];
    const float bbp = bb[p];

    const int* ej = edge_index + (size_t)p * 2 * N_EDGES;
    const int* ei = ej + N_EDGES;
    float* outp = out + (size_t)p * N_EDGES;

    const int e_blk = blockIdx.x * 320;
    const int eoff  = wave * 8 + grp;
    const int roff  = sub * 8;

    #pragma unroll
    for (int it = 0; it < 5; ++it) {
        const int e1 = e_blk + it * 64 + eoff;
        const int e2 = e1 + 32;
        const int j1 = __builtin_nontemporal_load(ej + e1);
        const int i1 = __builtin_nontemporal_load(ei + e1);
        const int j2 = __builtin_nontemporal_load(ej + e2);
        const int i2 = __builtin_nontemporal_load(ei + e2);

        const uint4* rj1 = (const uint4*)(xh + ((size_t)j1 << 6) + roff);
        const uint4* ri1 = (const uint4*)(xh + ((size_t)i1 << 6) + roff);
        const uint4* rj2 = (const uint4*)(xh + ((size_t)j2 << 6) + roff);
        const uint4* ri2 = (const uint4*)(xh + ((size_t)i2 << 6) + roff);
        uint4 a0 = rj1[0], a1 = rj1[1];
        uint4 b0 = ri1[0], b1 = ri1[1];
        uint4 c0 = rj2[0], c1 = rj2[1];
        uint4 d0 = ri2[0], d1 = ri2[1];

        float h0a, h1a, h2a, h0b, h1b, h2b;
        dot3_8(a0, a1, b0, b1, wa, h0a, h1a, h2a);
        dot3_8(c0, c1, d0, d1, wa, h0b, h1b, h2b);

        h0a += swz<0x041F>(h0a); h1a += swz<0x041F>(h1a); h2a += swz<0x041F>(h2a);
        h0b += swz<0x041F>(h0b); h1b += swz<0x041F>(h1b); h2b += swz<0x041F>(h2b);
        h0a += swz<0x081F>(h0a); h1a += swz<0x081F>(h1a); h2a += swz<0x081F>(h2a);
        h0b += swz<0x081F>(h0b); h1b += swz<0x081F>(h1b); h2b += swz<0x081F>(h2b);
        h0a += swz<0x101F>(h0a); h1a += swz<0x101F>(h1a); h2a += swz<0x101F>(h2a);
        h0b += swz<0x101F>(h0b); h1b += swz<0x101F>(h1b); h2b += swz<0x101F>(h2b);

        if (sub == 0) {
            float r0 = fmaxf(h0a + ba0, 0.f);
            float r1 = fmaxf(h1a + ba1, 0.f);
            float r2 = fmaxf(h2a + ba2, 0.f);
            float s  = fmaf(r0, wb0, fmaf(r1, wb1, fmaf(r2, wb2, bbp)));
            __builtin_nontemporal_store(1.f / (1.f + __expf(-s)), outp + e1);
            r0 = fmaxf(h0b + ba0, 0.f);
            r1 = fmaxf(h1b + ba1, 0.f);
            r2 = fmaxf(h2b + ba2, 0.f);
            s  = fmaf(r0, wb0, fmaf(r1, wb1, fmaf(r2, wb2, bbp)));
            __builtin_nontemporal_store(1.f / (1.f + __expf(-s)), outp + e2);
        }
    }
}

// ---- fp32 fallback (no workspace) ----
__global__ __launch_bounds__(256) void adj_kernel_f32(
    const float* __restrict__ x,
    const int*   __restrict__ edge_index,
    const float* __restrict__ Wa,
    const float* __restrict__ ba,
    const float* __restrict__ Wb,
    const float* __restrict__ bb,
    float* __restrict__ out)
{
    const int p    = blockIdx.y;
    const int tid  = threadIdx.x;
    const int lane = tid & 63;
    const int wave = tid >> 6;
    const int sub  = lane & 15;
    const int grp  = lane >> 4;
    const int f0 = sub * 8;

    const float* Wap = Wa + (size_t)p * N_FEAT * 3;
    float wa0[8], wa1[8], wa2[8];
    #pragma unroll
    for (int k = 0; k < 8; ++k) {
        wa0[k] = Wap[(f0 + k) * 3 + 0];
        wa1[k] = Wap[(f0 + k) * 3 + 1];
        wa2[k] = Wap[(f0 + k) * 3 + 2];
    }
    const float ba0 = ba[p * 3 + 0], ba1 = ba[p * 3 + 1], ba2 = ba[p * 3 + 2];
    const float wb0 = Wb[p * 3 + 0], wb1 = Wb[p * 3 + 1], wb2 = Wb[p * 3 + 2];
    const float bbp = bb[p];

    const int e = blockIdx.x * 16 + wave * 4 + grp;
    const int* ej = edge_index + (size_t)p * 2 * N_EDGES;
    const int* ei = ej + N_EDGES;
    const int j = ej[e];
    const int i = ei[e];

    const float4* xj = (const float4*)(x + (size_t)j * N_FEAT + f0);
    const float4* xi = (const float4*)(x + (size_t)i * N_FEAT + f0);
    float4 a0 = xj[0], a1 = xj[1];
    float4 b0 = xi[0], b1 = xi[1];

    float d[8];
    d[0] = fabsf(a0.x - b0.x); d[1] = fabsf(a0.y - b0.y);
    d[2] = fabsf(a0.z - b0.z); d[3] = fabsf(a0.w - b0.w);
    d[4] = fabsf(a1.x - b1.x); d[5] = fabsf(a1.y - b1.y);
    d[6] = fabsf(a1.z - b1.z); d[7] = fabsf(a1.w - b1.w);

    float h0 = 0.f, h1 = 0.f, h2 = 0.f;
    #pragma unroll
    for (int k = 0; k < 8; ++k) {
        h0 = fmaf(d[k], wa0[k], h0);
        h1 = fmaf(d[k], wa1[k], h1);
        h2 = fmaf(d[k], wa2[k], h2);
    }
    #pragma unroll
    for (int m = 1; m < 16; m <<= 1) {
        h0 += __shfl_xor(h0, m, 64);
        h1 += __shfl_xor(h1, m, 64);
        h2 += __shfl_xor(h2, m, 64);
    }
    if (sub == 0) {
        float r0 = fmaxf(h0 + ba0, 0.f);
        float r1 = fmaxf(h1 + ba1, 0.f);
        float r2 = fmaxf(h2 + ba2, 0.f);
        float s  = fmaf(r0, wb0, fmaf(r1, wb1, fmaf(r2, wb2, bbp)));
        float w  = 1.f / (1.f + expf(-s));
        out[(size_t)p * N_EDGES + e] = w;
    }
}

extern "C" void kernel_launch(void* const* d_in, const int* in_sizes, int n_in,
                              void* d_out, int out_size, void* d_ws, size_t ws_size,
                              hipStream_t stream) {
    const float* x          = (const float*)d_in[0];
    const int*   edge_index = (const int*)d_in[1];
    const float* Wa         = (const float*)d_in[2];
    const float* ba         = (const float*)d_in[3];
    const float* Wb         = (const float*)d_in[4];
    const float* bb         = (const float*)d_in[5];
    float* out = (float*)d_out;

    const size_t x_bytes    = (size_t)N_NODES * N_FEAT * 2;                 // 12,800,000
    const size_t su_bytes   = (size_t)N_POWERS * NB64 * CAP64 * 8;          // 15,728,640
    const size_t wah_bytes  = 2304;
    const size_t hist_bytes = (size_t)N_POWERS * NB64 * NCHUNK * 4;         // 225,024
    const size_t cur_bytes  = NB64 * N_POWERS * 4;
    const size_t need_full  = x_bytes + su_bytes + wah_bytes + hist_bytes + cur_bytes;

    if (ws_size >= need_full) {
        char* w = (char*)d_ws;
        unsigned* xh = (unsigned*)w;
        unsigned long long* su = (unsigned long long*)(w + x_bytes);
        unsigned* wah = (unsigned*)(w + x_bytes + su_bytes);
        int* hist = (int*)(w + x_bytes + su_bytes + wah_bytes);
        int* cur  = (int*)(w + x_bytes + su_bytes + wah_bytes + hist_bytes);

        conv_x_plain<<<N_NODES * N_FEAT / 2048, 256, 0, stream>>>(x, xh, Wa, wah);
        hist_kernel<<<dim3(NCHUNK, N_POWERS), 256, 0, stream>>>(edge_index, hist);
        scan_hist<<<NB64 * N_POWERS, 64, 0, stream>>>(hist, cur);
        scatter_pass<<<dim3(NCHUNK, N_POWERS), 256, 0, stream>>>(edge_index, hist, su);
        dim3 grid(NJB * NIB * (CAP64 / EDGES_PER_BLK), N_POWERS);   // (2048, 3)
        adj_kernel_f16s<<<grid, 256, 0, stream>>>(xh, su, cur, wah, ba, Wb, bb, out);
    } else if (ws_size >= x_bytes + wah_bytes) {
        unsigned* xh  = (unsigned*)d_ws;
        unsigned* wah = (unsigned*)((char*)d_ws + x_bytes);
        conv_x_plain<<<N_NODES * N_FEAT / 2048, 256, 0, stream>>>(x, xh, Wa, wah);
        dim3 grid(N_EDGES / 320, N_POWERS);
        adj_kernel_f16<<<grid, 256, 0, stream>>>(xh, wah, edge_index, ba, Wb, bb, out);
    } else {
        dim3 grid((N_EDGES + 15) / 16, N_POWERS);
        adj_kernel_f32<<<grid, 256, 0, stream>>>(x, edge_index, Wa, ba, Wb, bb, out);
    }
}